// Round 3
// baseline (280.736 us; speedup 1.0000x reference)
//
#include <hip/hip_runtime.h>
#include <math.h>

#define IMG 4320
#define H2D 2160
#define FMD 1080
#define FF 21

// ---------------- workspace layout (float units) ----------------
#define H2_OFF    0                       // 2*2160*2160 = 9331200
#define RED_OFF   9331200                 // 1080*1080   = 1166400
#define Y_OFF     10497600                // 2*21*21     = 882
#define PROPS_OFF 10498482                // 20
#define RECTS_OFF 10498502                // 80 ints
#define POOL_OFF  10498582                // 20 uints

// ============ K1: conv1 -> conv2 -> maxpool2  (x -> h2 [2,2160,2160]) ============
// Block tile: conv2 region 30x30 -> pooled 15x15. c1 tile 32x32, x tile 34x34.
// grid 144x144. Weights loaded in 9-value JIT chunks (small scalar live ranges).
__global__ __launch_bounds__(256) void k1_backbone1(
    const float* __restrict__ x,
    const float* __restrict__ w1, const float* __restrict__ b1,
    const float* __restrict__ w2, const float* __restrict__ b2,
    float* __restrict__ h2) {
  __shared__ float xs[3][34][36];   // global (gy0+r, gx0+c), gy0 = by*30-2
  __shared__ float c1s[3][32][36];  // global (by*30-1+r, bx*30-1+c)
  const int tid = threadIdx.x;
  const int bx = blockIdx.x, by = blockIdx.y;
  const int gy0 = by * 30 - 2, gx0 = bx * 30 - 2;

  // ---- stage 1: load x tile (3 x 34 x 36incl-pad), zero outside image ----
  for (int l = tid; l < 3 * 34 * 36; l += 256) {
    int c = l / 1224, rem = l % 1224, r = rem / 36, cc = rem % 36;
    int gy = gy0 + r, gx = gx0 + cc;
    float v = 0.f;
    if ((unsigned)gy < IMG && (unsigned)gx < IMG)
      v = x[(size_t)c * IMG * IMG + (size_t)gy * IMG + gx];
    xs[c][r][cc] = v;
  }
  __syncthreads();

  // ---- stage 2: conv1, one 1x4 segment per thread (32 rows x 8 segs) ----
  {
    const int r = tid >> 3;            // 0..31
    const int c4 = (tid & 7) << 2;     // 0..28
    float acc[3][4];
    #pragma unroll
    for (int oc = 0; oc < 3; ++oc) {
      const float bb = b1[oc];
      #pragma unroll
      for (int j = 0; j < 4; ++j) acc[oc][j] = bb;
    }
    #pragma unroll
    for (int ic = 0; ic < 3; ++ic) {
      float xr[3][8];
      #pragma unroll
      for (int dy = 0; dy < 3; ++dy) {
        const float4 q0 = *(const float4*)&xs[ic][r + dy][c4];
        const float4 q1 = *(const float4*)&xs[ic][r + dy][c4 + 4];
        xr[dy][0] = q0.x; xr[dy][1] = q0.y; xr[dy][2] = q0.z; xr[dy][3] = q0.w;
        xr[dy][4] = q1.x; xr[dy][5] = q1.y; xr[dy][6] = q1.z; xr[dy][7] = q1.w;
      }
      #pragma unroll
      for (int oc = 0; oc < 3; ++oc) {
        float w9[9];
        #pragma unroll
        for (int q = 0; q < 9; ++q) w9[q] = w1[oc * 27 + ic * 9 + q];
        #pragma unroll
        for (int dy = 0; dy < 3; ++dy)
          #pragma unroll
          for (int dx = 0; dx < 3; ++dx) {
            const float w = w9[dy * 3 + dx];
            #pragma unroll
            for (int j = 0; j < 4; ++j) acc[oc][j] += xr[dy][j + dx] * w;
          }
      }
    }
    // zero positions outside the image (conv2's implicit zero-padding)
    const int gy = by * 30 - 1 + r;
    const bool rOK = (unsigned)gy < IMG;
    const int gxb = bx * 30 - 1 + c4;
    #pragma unroll
    for (int oc = 0; oc < 3; ++oc) {
      float4 o;
      o.x = (rOK && (unsigned)(gxb + 0) < IMG) ? acc[oc][0] : 0.f;
      o.y = (rOK && (unsigned)(gxb + 1) < IMG) ? acc[oc][1] : 0.f;
      o.z = (rOK && (unsigned)(gxb + 2) < IMG) ? acc[oc][2] : 0.f;
      o.w = (rOK && (unsigned)(gxb + 3) < IMG) ? acc[oc][3] : 0.f;
      *(float4*)&c1s[oc][r][c4] = o;
    }
  }
  __syncthreads();

  // ---- stage 3: conv2 (3->2) + 2x2 maxpool, one pooled pixel per thread ----
  const int ty = tid >> 4, tx = tid & 15;
  if (ty < 15 && tx < 15) {
    float cr[3][4][4];
    #pragma unroll
    for (int ic = 0; ic < 3; ++ic)
      #pragma unroll
      for (int rr = 0; rr < 4; ++rr) {
        const float2 p0 = *(const float2*)&c1s[ic][2 * ty + rr][2 * tx];
        const float2 p1 = *(const float2*)&c1s[ic][2 * ty + rr][2 * tx + 2];
        cr[ic][rr][0] = p0.x; cr[ic][rr][1] = p0.y;
        cr[ic][rr][2] = p1.x; cr[ic][rr][3] = p1.y;
      }
    float mm[2];
    #pragma unroll
    for (int oc = 0; oc < 2; ++oc) {
      float a[4];
      const float bb = b2[oc];
      #pragma unroll
      for (int p = 0; p < 4; ++p) a[p] = bb;
      #pragma unroll
      for (int ic = 0; ic < 3; ++ic) {
        float w9[9];
        #pragma unroll
        for (int q = 0; q < 9; ++q) w9[q] = w2[oc * 27 + ic * 9 + q];
        #pragma unroll
        for (int dy = 0; dy < 3; ++dy)
          #pragma unroll
          for (int dx = 0; dx < 3; ++dx) {
            const float w = w9[dy * 3 + dx];
            #pragma unroll
            for (int sy = 0; sy < 2; ++sy)
              #pragma unroll
              for (int sx = 0; sx < 2; ++sx)
                a[sy * 2 + sx] += cr[ic][sy + dy][sx + dx] * w;
          }
      }
      mm[oc] = fmaxf(fmaxf(a[0], a[1]), fmaxf(a[2], a[3]));
    }
    const size_t o = (size_t)(by * 15 + ty) * H2D + (bx * 15 + tx);
    h2[o] = mm[0];
    h2[(size_t)H2D * H2D + o] = mm[1];
  }
}

// ============ K2: conv3 -> conv4 -> maxpool2  (h2 -> reduced [1080,1080]) ============
__global__ __launch_bounds__(256) void k2_backbone2(
    const float* __restrict__ h2,
    const float* __restrict__ w3, const float* __restrict__ b3,
    const float* __restrict__ w4, const float* __restrict__ b4,
    float* __restrict__ red) {
  __shared__ float hs[2][34][36];
  __shared__ float c3s[2][32][36];
  const int tid = threadIdx.x;
  const int bx = blockIdx.x, by = blockIdx.y;
  const int gy0 = by * 30 - 2, gx0 = bx * 30 - 2;

  for (int l = tid; l < 2 * 34 * 36; l += 256) {
    int c = l / 1224, rem = l % 1224, r = rem / 36, cc = rem % 36;
    int gy = gy0 + r, gx = gx0 + cc;
    float v = 0.f;
    if ((unsigned)gy < H2D && (unsigned)gx < H2D)
      v = h2[(size_t)c * H2D * H2D + (size_t)gy * H2D + gx];
    hs[c][r][cc] = v;
  }
  __syncthreads();

  {
    const int r = tid >> 3;
    const int c4 = (tid & 7) << 2;
    float acc[2][4];
    #pragma unroll
    for (int oc = 0; oc < 2; ++oc) {
      const float bb = b3[oc];
      #pragma unroll
      for (int j = 0; j < 4; ++j) acc[oc][j] = bb;
    }
    #pragma unroll
    for (int ic = 0; ic < 2; ++ic) {
      float xr[3][8];
      #pragma unroll
      for (int dy = 0; dy < 3; ++dy) {
        const float4 q0 = *(const float4*)&hs[ic][r + dy][c4];
        const float4 q1 = *(const float4*)&hs[ic][r + dy][c4 + 4];
        xr[dy][0] = q0.x; xr[dy][1] = q0.y; xr[dy][2] = q0.z; xr[dy][3] = q0.w;
        xr[dy][4] = q1.x; xr[dy][5] = q1.y; xr[dy][6] = q1.z; xr[dy][7] = q1.w;
      }
      #pragma unroll
      for (int oc = 0; oc < 2; ++oc) {
        float w9[9];
        #pragma unroll
        for (int q = 0; q < 9; ++q) w9[q] = w3[oc * 18 + ic * 9 + q];
        #pragma unroll
        for (int dy = 0; dy < 3; ++dy)
          #pragma unroll
          for (int dx = 0; dx < 3; ++dx) {
            const float w = w9[dy * 3 + dx];
            #pragma unroll
            for (int j = 0; j < 4; ++j) acc[oc][j] += xr[dy][j + dx] * w;
          }
      }
    }
    const int gy = by * 30 - 1 + r;
    const bool rOK = (unsigned)gy < H2D;
    const int gxb = bx * 30 - 1 + c4;
    #pragma unroll
    for (int oc = 0; oc < 2; ++oc) {
      float4 o;
      o.x = (rOK && (unsigned)(gxb + 0) < H2D) ? acc[oc][0] : 0.f;
      o.y = (rOK && (unsigned)(gxb + 1) < H2D) ? acc[oc][1] : 0.f;
      o.z = (rOK && (unsigned)(gxb + 2) < H2D) ? acc[oc][2] : 0.f;
      o.w = (rOK && (unsigned)(gxb + 3) < H2D) ? acc[oc][3] : 0.f;
      *(float4*)&c3s[oc][r][c4] = o;
    }
  }
  __syncthreads();

  const int ty = tid >> 4, tx = tid & 15;
  if (ty < 15 && tx < 15) {
    float cr[2][4][4];
    #pragma unroll
    for (int ic = 0; ic < 2; ++ic)
      #pragma unroll
      for (int rr = 0; rr < 4; ++rr) {
        const float2 p0 = *(const float2*)&c3s[ic][2 * ty + rr][2 * tx];
        const float2 p1 = *(const float2*)&c3s[ic][2 * ty + rr][2 * tx + 2];
        cr[ic][rr][0] = p0.x; cr[ic][rr][1] = p0.y;
        cr[ic][rr][2] = p1.x; cr[ic][rr][3] = p1.y;
      }
    float a[4];
    const float bb = b4[0];
    #pragma unroll
    for (int p = 0; p < 4; ++p) a[p] = bb;
    #pragma unroll
    for (int ic = 0; ic < 2; ++ic) {
      float w9[9];
      #pragma unroll
      for (int q = 0; q < 9; ++q) w9[q] = w4[ic * 9 + q];
      #pragma unroll
      for (int dy = 0; dy < 3; ++dy)
        #pragma unroll
        for (int dx = 0; dx < 3; ++dx) {
          const float w = w9[dy * 3 + dx];
          #pragma unroll
          for (int sy = 0; sy < 2; ++sy)
            #pragma unroll
            for (int sx = 0; sx < 2; ++sx)
              a[sy * 2 + sx] += cr[ic][sy + dy][sx + dx] * w;
        }
    }
    const float m = fmaxf(fmaxf(a[0], a[1]), fmaxf(a[2], a[3]));
    red[(size_t)(by * 15 + ty) * FMD + (bx * 15 + tx)] = m;
  }
}

// ============ K3: rpn_conv (50x50, stride 50)  (reduced -> y [2,21,21]) ============
__global__ __launch_bounds__(256) void k3_rpnconv(
    const float* __restrict__ red,
    const float* __restrict__ w, const float* __restrict__ b,
    float* __restrict__ y) {
  __shared__ float part[256];
  const int cell = blockIdx.x;
  const int i = cell / FF, j = cell % FF;
  const int tid = threadIdx.x;
  float a0 = 0.f, a1 = 0.f;
  for (int t = tid; t < 2500; t += 256) {
    int ay = t / 50, ax = t % 50;
    float v = red[(size_t)(50 * i + ay) * FMD + 50 * j + ax];
    a0 += v * w[t];
    a1 += v * w[2500 + t];
  }
  part[tid] = a0;
  __syncthreads();
  for (int s = 128; s > 0; s >>= 1) {
    if (tid < s) part[tid] += part[tid + s];
    __syncthreads();
  }
  if (tid == 0) y[cell] = part[0] + b[0];
  __syncthreads();
  part[tid] = a1;
  __syncthreads();
  for (int s = 128; s > 0; s >>= 1) {
    if (tid < s) part[tid] += part[tid + s];
    __syncthreads();
  }
  if (tid == 0) y[441 + cell] = part[0] + b[1];
}

// ============ K4: rpn heads, selection (faithful masked-select bug),
//               proposals, RoI rects, pooled-init ============
__global__ __launch_bounds__(512) void k4_select(
    const float* __restrict__ y,
    const float* __restrict__ bbw, const float* __restrict__ bbb,
    const float* __restrict__ clw, const float* __restrict__ clb,
    float* __restrict__ props_out, int* __restrict__ rects,
    unsigned* __restrict__ pooled_m) {
  __shared__ float ys[2][23][23];
  __shared__ unsigned char flag[6][441];
  __shared__ short pos[6][20];
  __shared__ int cnt[6];
  __shared__ int selT[20];
  __shared__ float offv[20], anchv[20];
  const int tid = threadIdx.x;
  for (int l = tid; l < 2 * 23 * 23; l += 512) ((float*)ys)[l] = 0.f;
  __syncthreads();
  for (int l = tid; l < 2 * 441; l += 512) {
    int c = l / 441, p = l % 441;
    ys[c][p / 21 + 1][p % 21 + 1] = y[l];
  }
  __syncthreads();
  for (int l = tid; l < 6 * 441; l += 512) {
    int a = l / 441, p = l % 441, i = p / 21, j = p % 21;
    float v = clb[a];
    #pragma unroll
    for (int c2 = 0; c2 < 2; c2++)
      #pragma unroll
      for (int dy = 0; dy < 3; dy++)
        #pragma unroll
        for (int dx = 0; dx < 3; dx++)
          v += ys[c2][i + dy][j + dx] * clw[a * 18 + c2 * 9 + dy * 3 + dx];
    flag[a][p] = (tanhf(v) > 0.95f) ? 1 : 0;
  }
  __syncthreads();
  if (tid < 6) {
    int c = 0;
    for (int p = 0; p < 441; p++)
      if (flag[tid][p]) {
        if (c < 20) pos[tid][c] = (short)p;
        c++;
      }
    cnt[tid] = c;
  }
  __syncthreads();
  if (tid == 0) {
    int s = 0;
    for (int g = 0; g < 24 && s < 20; g++) {
      int a = g >> 2;
      int take = cnt[a] < 20 - s ? cnt[a] : 20 - s;
      for (int r = 0; r < take; r++) selT[s++] = g * 441 + (int)pos[a][r];
    }
    if (s < 20) {
      for (int t = 0; t < 10584 && s < 20; t++) {
        int a = t / 1764, p = t % 441;
        if (!flag[a][p]) selT[s++] = t;
      }
    }
  }
  __syncthreads();
  if (tid < 20) {
    int t = selT[tid];
    int ch = t / 441, p = t % 441, i = p / 21, j = p % 21;
    int a = ch >> 2, c = ch & 3;
    float v = bbb[ch];
    #pragma unroll
    for (int c2 = 0; c2 < 2; c2++)
      #pragma unroll
      for (int dy = 0; dy < 3; dy++)
        #pragma unroll
        for (int dx = 0; dx < 3; dx++)
          v += ys[c2][i + dy][j + dx] * bbw[ch * 18 + c2 * 9 + dy * 3 + dx];
    offv[tid] = v;
    float sz = (a < 3) ? 1.f : 2.f;
    int am = a % 3;
    float ar = (am == 0) ? 0.5f : (am == 1 ? 1.f : 2.f);
    float base;
    if (c == 0) base = 0.f;
    else if (c == 1) base = sz * -(ar - 1.f) * 0.5f;
    else if (c == 2) base = sz;
    else base = sz * (1.f + (ar - 1.f) * 0.5f);
    anchv[tid] = base + ((c & 1) ? (float)j : (float)i);
  }
  __syncthreads();
  if (tid < 5) {
    int k = tid;
    float o0 = offv[4 * k], o1 = offv[4 * k + 1], o2 = offv[4 * k + 2], o3 = offv[4 * k + 3];
    float a0 = anchv[4 * k], a2 = anchv[4 * k + 2], a3 = anchv[4 * k + 3];
    float p0 = fminf(fmaxf(o0 + a0 - a2 * 0.5f, 0.f), 21.f) * 50.f;
    float p1 = fminf(fmaxf(o1 - a3 * 0.5f, 0.f), 21.f) * 50.f;
    float p2 = fminf(fmaxf(o2 + a0 + a2 * 0.5f, 0.f), 21.f) * 50.f;
    float p3 = fminf(fmaxf(o3 + a3 * 0.5f, 0.f), 21.f) * 50.f;
    props_out[k * 4 + 0] = p0;
    props_out[k * 4 + 1] = p1;
    props_out[k * 4 + 2] = p2;
    props_out[k * 4 + 3] = p3;
    float x1 = rintf(p0), y1 = rintf(p1), x2 = rintf(p2), y2 = rintf(p3);
    float bwf = fmaxf(x2 - x1 + 1.f, 1.f) * 0.5f;
    float bhf = fmaxf(y2 - y1 + 1.f, 1.f) * 0.5f;
    for (int ph = 0; ph < 2; ph++)
      for (int pw = 0; pw < 2; pw++) {
        int hsv = (int)fminf(fmaxf(floorf((float)ph * bhf) + y1, 0.f), 1080.f);
        int hev = (int)fminf(fmaxf(ceilf((float)(ph + 1) * bhf) + y1, 0.f), 1080.f);
        int wsv = (int)fminf(fmaxf(floorf((float)pw * bwf) + x1, 0.f), 1080.f);
        int wev = (int)fminf(fmaxf(ceilf((float)(pw + 1) * bwf) + x1, 0.f), 1080.f);
        int idx = k * 4 + ph * 2 + pw;
        rects[idx * 4 + 0] = hsv;
        rects[idx * 4 + 1] = hev;
        rects[idx * 4 + 2] = wsv;
        rects[idx * 4 + 3] = wev;
      }
  }
  if (tid >= 32 && tid < 52) pooled_m[tid - 32] = 0x007FFFFFu;  // mapped(-inf)
}

// ============ K5: RoI max pool (atomicMax on order-preserving uint map) ============
__global__ __launch_bounds__(256) void k5_roipool(
    const float* __restrict__ red, const int* __restrict__ rects,
    unsigned* __restrict__ pooled_m) {
  const int cell = blockIdx.x;
  const int hs = rects[cell * 4 + 0], he = rects[cell * 4 + 1];
  const int wss = rects[cell * 4 + 2], wee = rects[cell * 4 + 3];
  const int nr = he - hs;
  if (nr <= 0 || wee <= wss) return;
  const int slice = blockIdx.y, nslice = gridDim.y;
  const int r0 = hs + (int)((long)nr * slice / nslice);
  const int r1 = hs + (int)((long)nr * (slice + 1) / nslice);
  float m = -INFINITY;
  for (int r = r0; r < r1; r++)
    for (int c = wss + (int)threadIdx.x; c < wee; c += 256)
      m = fmaxf(m, red[(size_t)r * FMD + c]);
  __shared__ float part[256];
  part[threadIdx.x] = m;
  __syncthreads();
  for (int s = 128; s > 0; s >>= 1) {
    if ((int)threadIdx.x < s) part[threadIdx.x] = fmaxf(part[threadIdx.x], part[threadIdx.x + s]);
    __syncthreads();
  }
  if (threadIdx.x == 0 && part[0] > -INFINITY) {
    unsigned u = __float_as_uint(part[0]);
    u = (u & 0x80000000u) ? ~u : (u | 0x80000000u);
    atomicMax(&pooled_m[cell], u);
  }
}

// ============ K6: fc / box / cls heads -> d_out (30 floats) ============
__global__ void k6_heads(
    const unsigned* __restrict__ pooled_m, const float* __restrict__ props,
    const float* __restrict__ fcw, const float* __restrict__ fcb,
    const float* __restrict__ bxw, const float* __restrict__ bxb,
    const float* __restrict__ clw, const float* __restrict__ clb,
    float* __restrict__ out) {
  if (threadIdx.x != 0 || blockIdx.x != 0) return;
  float pooled[5][4];
  for (int i = 0; i < 20; i++) {
    unsigned u = pooled_m[i];
    float f = (u & 0x80000000u) ? __uint_as_float(u ^ 0x80000000u) : __uint_as_float(~u);
    if (!isfinite(f)) f = 0.f;
    pooled[i / 4][i % 4] = f;
  }
  for (int k = 0; k < 5; k++) {
    float fc[12];
    for (int m = 0; m < 12; m++) {
      float v = fcb[m];
      for (int n = 0; n < 4; n++) v += pooled[k][n] * fcw[m * 4 + n];
      fc[m] = v;
    }
    float bo[4];
    for (int c = 0; c < 4; c++) {
      float v = bxb[c];
      for (int m = 0; m < 12; m++) v += fc[m] * bxw[c * 12 + m];
      bo[c] = v;
    }
    float p0 = props[k * 4], p1 = props[k * 4 + 1], p2 = props[k * 4 + 2], p3 = props[k * 4 + 3];
    out[k * 4 + 0] = fminf(fmaxf(p0 + bo[0] - bo[2] * 0.5f, 0.f), 3.f);
    out[k * 4 + 1] = fminf(fmaxf(p1 - bo[3] * 0.5f, 0.f), 1.f);
    out[k * 4 + 2] = fminf(fmaxf(p2 + bo[0] + bo[2] * 0.5f, 0.f), 3.f);
    out[k * 4 + 3] = fminf(fmaxf(p3 + bo[3] * 0.5f, 0.f), 1.f);
    float l0 = clb[0], l1 = clb[1];
    for (int m = 0; m < 12; m++) {
      l0 += fc[m] * clw[m];
      l1 += fc[m] * clw[12 + m];
    }
    float mx = fmaxf(l0, l1);
    float e0 = expf(l0 - mx), e1 = expf(l1 - mx);
    out[20 + k * 2 + 0] = e0 / (e0 + e1);
    out[20 + k * 2 + 1] = e1 / (e0 + e1);
  }
}

extern "C" void kernel_launch(void* const* d_in, const int* in_sizes, int n_in,
                              void* d_out, int out_size, void* d_ws, size_t ws_size,
                              hipStream_t stream) {
  const float* x   = (const float*)d_in[0];
  const float* w1  = (const float*)d_in[1];
  const float* b1  = (const float*)d_in[2];
  const float* w2  = (const float*)d_in[3];
  const float* b2  = (const float*)d_in[4];
  const float* w3  = (const float*)d_in[5];
  const float* b3  = (const float*)d_in[6];
  const float* w4  = (const float*)d_in[7];
  const float* b4  = (const float*)d_in[8];
  const float* rw  = (const float*)d_in[9];
  const float* rb  = (const float*)d_in[10];
  const float* bbw = (const float*)d_in[11];
  const float* bbb = (const float*)d_in[12];
  const float* clw = (const float*)d_in[13];
  const float* clb = (const float*)d_in[14];
  const float* fcw = (const float*)d_in[15];
  const float* fcb = (const float*)d_in[16];
  const float* bxw = (const float*)d_in[17];
  const float* bxb = (const float*)d_in[18];
  const float* c2w = (const float*)d_in[19];
  const float* c2b = (const float*)d_in[20];

  float* ws = (float*)d_ws;
  float* h2 = ws + H2_OFF;
  float* red = ws + RED_OFF;
  float* y = ws + Y_OFF;
  float* props = ws + PROPS_OFF;
  int* rects = (int*)(ws + RECTS_OFF);
  unsigned* pooled_m = (unsigned*)(ws + POOL_OFF);

  k1_backbone1<<<dim3(144, 144), 256, 0, stream>>>(x, w1, b1, w2, b2, h2);
  k2_backbone2<<<dim3(72, 72), 256, 0, stream>>>(h2, w3, b3, w4, b4, red);
  k3_rpnconv<<<441, 256, 0, stream>>>(red, rw, rb, y);
  k4_select<<<1, 512, 0, stream>>>(y, bbw, bbb, clw, clb, props, rects, pooled_m);
  k5_roipool<<<dim3(20, 16), 256, 0, stream>>>(red, rects, pooled_m);
  k6_heads<<<1, 64, 0, stream>>>(pooled_m, props, fcw, fcb, bxw, bxb, c2w, c2b,
                                 (float*)d_out);
}

// Round 4
// 275.753 us; speedup vs baseline: 1.0181x; 1.0181x over previous
//
#include <hip/hip_runtime.h>
#include <math.h>

#define IMG 4320
#define H2D 2160
#define FMD 1080
#define FF 21

// ---------------- workspace layout (float units) ----------------
#define H2_OFF    0                       // 2*2160*2160 = 9331200
#define RED_OFF   9331200                 // 1080*1080   = 1166400
#define Y_OFF     10497600                // 2*21*21     = 882
#define PROPS_OFF 10498482                // 20
#define RECTS_OFF 10498502                // 80 ints
#define POOL_OFF  10498582                // 20 uints

// ============ K1: streaming conv1 -> conv2 -> maxpool2 (x -> h2 [2,2160,2160]) ============
// Wave-autonomous: each wave owns a 64-column strip (lane = conv1 column),
// streams 62 conv rows; x/c1 kept in 3-row register windows; +-1 column halo
// via __shfl. No barriers, no LDS tiles. 72x72 = 5184 wave-tasks, 30x30 pooled
// outputs each (72*30 = 2160 exact both dims).

#define K1_LOADX(S, GY) do {                                                  \
    const int gy_ = (GY);                                                     \
    if ((unsigned)gy_ < (unsigned)IMG) {                                      \
      const size_t rb_ = (size_t)gy_ * IMG + (size_t)colc;                    \
      _Pragma("unroll")                                                       \
      for (int c_ = 0; c_ < 3; ++c_) {                                        \
        float v_ = x[(size_t)c_ * IMG * IMG + rb_];                           \
        v_ = colOK ? v_ : 0.f;                                                \
        xm[S][c_] = v_;                                                       \
        xl[S][c_] = __shfl(v_, lane - 1);                                     \
        xr[S][c_] = __shfl(v_, lane + 1);                                     \
      }                                                                       \
    } else {                                                                  \
      _Pragma("unroll")                                                       \
      for (int c_ = 0; c_ < 3; ++c_) {                                        \
        xm[S][c_] = 0.f; xl[S][c_] = 0.f; xr[S][c_] = 0.f;                    \
      }                                                                       \
    }                                                                         \
  } while (0)

#define K1_SHIFTX() do {                                                      \
    _Pragma("unroll")                                                         \
    for (int c_ = 0; c_ < 3; ++c_) {                                          \
      xm[0][c_] = xm[1][c_]; xl[0][c_] = xl[1][c_]; xr[0][c_] = xr[1][c_];    \
      xm[1][c_] = xm[2][c_]; xl[1][c_] = xl[2][c_]; xr[1][c_] = xr[2][c_];    \
    }                                                                         \
  } while (0)

// conv1 row CROW from x slots 0,1,2 (= rows CROW-1, CROW, CROW+1)
#define K1_CONV1(DST, CROW) do {                                              \
    const int cr_ = (CROW);                                                   \
    if ((unsigned)cr_ < (unsigned)IMG) {                                      \
      _Pragma("unroll")                                                       \
      for (int oc_ = 0; oc_ < 3; ++oc_) {                                     \
        float a_ = B1[oc_];                                                   \
        _Pragma("unroll")                                                     \
        for (int ic_ = 0; ic_ < 3; ++ic_) {                                   \
          _Pragma("unroll")                                                   \
          for (int dy_ = 0; dy_ < 3; ++dy_) {                                 \
            a_ += xl[dy_][ic_] * W1[oc_*27 + ic_*9 + dy_*3 + 0];              \
            a_ += xm[dy_][ic_] * W1[oc_*27 + ic_*9 + dy_*3 + 1];              \
            a_ += xr[dy_][ic_] * W1[oc_*27 + ic_*9 + dy_*3 + 2];              \
          }                                                                   \
        }                                                                     \
        a_ = colOK ? a_ : 0.f;                                                \
        cm[DST][oc_] = a_;                                                    \
        cl[DST][oc_] = __shfl(a_, lane - 1);                                  \
        cr[DST][oc_] = __shfl(a_, lane + 1);                                  \
      }                                                                       \
    } else {                                                                  \
      _Pragma("unroll")                                                       \
      for (int oc_ = 0; oc_ < 3; ++oc_) {                                     \
        cm[DST][oc_] = 0.f; cl[DST][oc_] = 0.f; cr[DST][oc_] = 0.f;           \
      }                                                                       \
    }                                                                         \
  } while (0)

// conv2 row from c1 slots SA,SB,SC (= c1 rows R-1, R, R+1)
#define K1_CONV2(ACC, SA, SB, SC) do {                                        \
    _Pragma("unroll")                                                         \
    for (int oc_ = 0; oc_ < 2; ++oc_) {                                       \
      float a_ = B2[oc_];                                                     \
      _Pragma("unroll")                                                       \
      for (int ic_ = 0; ic_ < 3; ++ic_) {                                     \
        a_ += cl[SA][ic_] * W2[oc_*27 + ic_*9 + 0];                           \
        a_ += cm[SA][ic_] * W2[oc_*27 + ic_*9 + 1];                           \
        a_ += cr[SA][ic_] * W2[oc_*27 + ic_*9 + 2];                           \
        a_ += cl[SB][ic_] * W2[oc_*27 + ic_*9 + 3];                           \
        a_ += cm[SB][ic_] * W2[oc_*27 + ic_*9 + 4];                           \
        a_ += cr[SB][ic_] * W2[oc_*27 + ic_*9 + 5];                           \
        a_ += cl[SC][ic_] * W2[oc_*27 + ic_*9 + 6];                           \
        a_ += cm[SC][ic_] * W2[oc_*27 + ic_*9 + 7];                           \
        a_ += cr[SC][ic_] * W2[oc_*27 + ic_*9 + 8];                           \
      }                                                                       \
      ACC[oc_] = a_;                                                          \
    }                                                                         \
  } while (0)

__global__ __launch_bounds__(256) void k1_stream(
    const float* __restrict__ x,
    const float* __restrict__ w1, const float* __restrict__ b1,
    const float* __restrict__ w2, const float* __restrict__ b2,
    float* __restrict__ h2) {
  const int lane = threadIdx.x & 63;
  const int wid  = blockIdx.x * 4 + (threadIdx.x >> 6);
  const int sx = wid % 72, sy = wid / 72;
  const int col  = 60 * sx - 2 + lane;          // this lane's conv1/x column
  const bool colOK = (unsigned)col < (unsigned)IMG;
  const int colc = colOK ? col : 0;
  const int py0 = 30 * sy;                      // first pooled row of band
  const int R0  = 2 * py0;                      // first conv row of band

  float W1[81], W2[54], B1[3], B2[2];
  #pragma unroll
  for (int i = 0; i < 81; ++i) W1[i] = w1[i];
  #pragma unroll
  for (int i = 0; i < 54; ++i) W2[i] = w2[i];
  B1[0] = b1[0]; B1[1] = b1[1]; B1[2] = b1[2];
  B2[0] = b2[0]; B2[1] = b2[1];

  float xm[3][3], xl[3][3], xr[3][3];   // x rolling window [slot][ch]
  float cm[4][3], cl[4][3], cr[4][3];   // c1 slots [slot][oc]

  // prologue: x rows R0-2, R0-1, R0 ; c1 rows R0-1 (slot0), R0 (slot1)
  K1_LOADX(0, R0 - 2);
  K1_LOADX(1, R0 - 1);
  K1_LOADX(2, R0);
  K1_CONV1(0, R0 - 1);
  K1_SHIFTX();
  K1_LOADX(2, R0 + 1);
  K1_CONV1(1, R0);

  for (int k = 0; k < 30; ++k) {
    const int R = R0 + 2 * k;
    K1_SHIFTX();
    K1_LOADX(2, R + 2);
    K1_CONV1(2, R + 1);                 // CC = c1 row R+1
    float acc0[2], acc1[2];
    K1_CONV2(acc0, 0, 1, 2);            // conv2 row R
    K1_SHIFTX();
    K1_LOADX(2, R + 3);
    K1_CONV1(3, R + 2);                 // CD = c1 row R+2
    K1_CONV2(acc1, 1, 2, 3);            // conv2 row R+1

    // 2x2 maxpool: vertical max, horizontal pair max (lanes e,e+1), compact, store
    #pragma unroll
    for (int oc_ = 0; oc_ < 2; ++oc_) {
      float vmx = fmaxf(acc0[oc_], acc1[oc_]);
      vmx = fmaxf(vmx, __shfl_xor(vmx, 1));
      const float pc = __shfl(vmx, 2 * lane - 2);
      if (lane >= 2 && lane < 32) {
        const size_t o = (size_t)oc_ * H2D * H2D + (size_t)(py0 + k) * H2D +
                         (size_t)(30 * sx + lane - 2);
        h2[o] = pc;
      }
    }
    // rotate c1: slot0 <- slot2, slot1 <- slot3
    #pragma unroll
    for (int q_ = 0; q_ < 3; ++q_) {
      cm[0][q_] = cm[2][q_]; cl[0][q_] = cl[2][q_]; cr[0][q_] = cr[2][q_];
      cm[1][q_] = cm[3][q_]; cl[1][q_] = cl[3][q_]; cr[1][q_] = cr[3][q_];
    }
  }
}

// ============ K2: conv3 -> conv4 -> maxpool2  (h2 -> reduced [1080,1080]) ============
__global__ __launch_bounds__(256) void k2_backbone2(
    const float* __restrict__ h2,
    const float* __restrict__ w3, const float* __restrict__ b3,
    const float* __restrict__ w4, const float* __restrict__ b4,
    float* __restrict__ red) {
  __shared__ float hs[2][34][36];
  __shared__ float c3s[2][32][36];
  const int tid = threadIdx.x;
  const int bx = blockIdx.x, by = blockIdx.y;
  const int gy0 = by * 30 - 2, gx0 = bx * 30 - 2;

  for (int l = tid; l < 2 * 34 * 36; l += 256) {
    int c = l / 1224, rem = l % 1224, r = rem / 36, cc = rem % 36;
    int gy = gy0 + r, gx = gx0 + cc;
    float v = 0.f;
    if ((unsigned)gy < H2D && (unsigned)gx < H2D)
      v = h2[(size_t)c * H2D * H2D + (size_t)gy * H2D + gx];
    hs[c][r][cc] = v;
  }
  __syncthreads();

  {
    const int r = tid >> 3;
    const int c4 = (tid & 7) << 2;
    float acc[2][4];
    #pragma unroll
    for (int oc = 0; oc < 2; ++oc) {
      const float bb = b3[oc];
      #pragma unroll
      for (int j = 0; j < 4; ++j) acc[oc][j] = bb;
    }
    #pragma unroll
    for (int ic = 0; ic < 2; ++ic) {
      float xr[3][8];
      #pragma unroll
      for (int dy = 0; dy < 3; ++dy) {
        const float4 q0 = *(const float4*)&hs[ic][r + dy][c4];
        const float4 q1 = *(const float4*)&hs[ic][r + dy][c4 + 4];
        xr[dy][0] = q0.x; xr[dy][1] = q0.y; xr[dy][2] = q0.z; xr[dy][3] = q0.w;
        xr[dy][4] = q1.x; xr[dy][5] = q1.y; xr[dy][6] = q1.z; xr[dy][7] = q1.w;
      }
      #pragma unroll
      for (int oc = 0; oc < 2; ++oc) {
        float w9[9];
        #pragma unroll
        for (int q = 0; q < 9; ++q) w9[q] = w3[oc * 18 + ic * 9 + q];
        #pragma unroll
        for (int dy = 0; dy < 3; ++dy)
          #pragma unroll
          for (int dx = 0; dx < 3; ++dx) {
            const float w = w9[dy * 3 + dx];
            #pragma unroll
            for (int j = 0; j < 4; ++j) acc[oc][j] += xr[dy][j + dx] * w;
          }
      }
    }
    const int gy = by * 30 - 1 + r;
    const bool rOK = (unsigned)gy < H2D;
    const int gxb = bx * 30 - 1 + c4;
    #pragma unroll
    for (int oc = 0; oc < 2; ++oc) {
      float4 o;
      o.x = (rOK && (unsigned)(gxb + 0) < H2D) ? acc[oc][0] : 0.f;
      o.y = (rOK && (unsigned)(gxb + 1) < H2D) ? acc[oc][1] : 0.f;
      o.z = (rOK && (unsigned)(gxb + 2) < H2D) ? acc[oc][2] : 0.f;
      o.w = (rOK && (unsigned)(gxb + 3) < H2D) ? acc[oc][3] : 0.f;
      *(float4*)&c3s[oc][r][c4] = o;
    }
  }
  __syncthreads();

  const int ty = tid >> 4, tx = tid & 15;
  if (ty < 15 && tx < 15) {
    float cr[2][4][4];
    #pragma unroll
    for (int ic = 0; ic < 2; ++ic)
      #pragma unroll
      for (int rr = 0; rr < 4; ++rr) {
        const float2 p0 = *(const float2*)&c3s[ic][2 * ty + rr][2 * tx];
        const float2 p1 = *(const float2*)&c3s[ic][2 * ty + rr][2 * tx + 2];
        cr[ic][rr][0] = p0.x; cr[ic][rr][1] = p0.y;
        cr[ic][rr][2] = p1.x; cr[ic][rr][3] = p1.y;
      }
    float a[4];
    const float bb = b4[0];
    #pragma unroll
    for (int p = 0; p < 4; ++p) a[p] = bb;
    #pragma unroll
    for (int ic = 0; ic < 2; ++ic) {
      float w9[9];
      #pragma unroll
      for (int q = 0; q < 9; ++q) w9[q] = w4[ic * 9 + q];
      #pragma unroll
      for (int dy = 0; dy < 3; ++dy)
        #pragma unroll
        for (int dx = 0; dx < 3; ++dx) {
          const float w = w9[dy * 3 + dx];
          #pragma unroll
          for (int sy = 0; sy < 2; ++sy)
            #pragma unroll
            for (int sx = 0; sx < 2; ++sx)
              a[sy * 2 + sx] += cr[ic][sy + dy][sx + dx] * w;
        }
    }
    const float m = fmaxf(fmaxf(a[0], a[1]), fmaxf(a[2], a[3]));
    red[(size_t)(by * 15 + ty) * FMD + (bx * 15 + tx)] = m;
  }
}

// ============ K3: rpn_conv (50x50, stride 50)  (reduced -> y [2,21,21]) ============
__global__ __launch_bounds__(256) void k3_rpnconv(
    const float* __restrict__ red,
    const float* __restrict__ w, const float* __restrict__ b,
    float* __restrict__ y) {
  __shared__ float part[256];
  const int cell = blockIdx.x;
  const int i = cell / FF, j = cell % FF;
  const int tid = threadIdx.x;
  float a0 = 0.f, a1 = 0.f;
  for (int t = tid; t < 2500; t += 256) {
    int ay = t / 50, ax = t % 50;
    float v = red[(size_t)(50 * i + ay) * FMD + 50 * j + ax];
    a0 += v * w[t];
    a1 += v * w[2500 + t];
  }
  part[tid] = a0;
  __syncthreads();
  for (int s = 128; s > 0; s >>= 1) {
    if (tid < s) part[tid] += part[tid + s];
    __syncthreads();
  }
  if (tid == 0) y[cell] = part[0] + b[0];
  __syncthreads();
  part[tid] = a1;
  __syncthreads();
  for (int s = 128; s > 0; s >>= 1) {
    if (tid < s) part[tid] += part[tid + s];
    __syncthreads();
  }
  if (tid == 0) y[441 + cell] = part[0] + b[1];
}

// ============ K4: rpn heads, selection (faithful masked-select bug),
//               proposals, RoI rects, pooled-init ============
__global__ __launch_bounds__(512) void k4_select(
    const float* __restrict__ y,
    const float* __restrict__ bbw, const float* __restrict__ bbb,
    const float* __restrict__ clw, const float* __restrict__ clb,
    float* __restrict__ props_out, int* __restrict__ rects,
    unsigned* __restrict__ pooled_m) {
  __shared__ float ys[2][23][23];
  __shared__ unsigned char flag[6][441];
  __shared__ short pos[6][20];
  __shared__ int cnt[6];
  __shared__ int selT[20];
  __shared__ float offv[20], anchv[20];
  const int tid = threadIdx.x;
  for (int l = tid; l < 2 * 23 * 23; l += 512) ((float*)ys)[l] = 0.f;
  __syncthreads();
  for (int l = tid; l < 2 * 441; l += 512) {
    int c = l / 441, p = l % 441;
    ys[c][p / 21 + 1][p % 21 + 1] = y[l];
  }
  __syncthreads();
  for (int l = tid; l < 6 * 441; l += 512) {
    int a = l / 441, p = l % 441, i = p / 21, j = p % 21;
    float v = clb[a];
    #pragma unroll
    for (int c2 = 0; c2 < 2; c2++)
      #pragma unroll
      for (int dy = 0; dy < 3; dy++)
        #pragma unroll
        for (int dx = 0; dx < 3; dx++)
          v += ys[c2][i + dy][j + dx] * clw[a * 18 + c2 * 9 + dy * 3 + dx];
    flag[a][p] = (tanhf(v) > 0.95f) ? 1 : 0;
  }
  __syncthreads();
  if (tid < 6) {
    int c = 0;
    for (int p = 0; p < 441; p++)
      if (flag[tid][p]) {
        if (c < 20) pos[tid][c] = (short)p;
        c++;
      }
    cnt[tid] = c;
  }
  __syncthreads();
  if (tid == 0) {
    int s = 0;
    for (int g = 0; g < 24 && s < 20; g++) {
      int a = g >> 2;
      int take = cnt[a] < 20 - s ? cnt[a] : 20 - s;
      for (int r = 0; r < take; r++) selT[s++] = g * 441 + (int)pos[a][r];
    }
    if (s < 20) {
      for (int t = 0; t < 10584 && s < 20; t++) {
        int a = t / 1764, p = t % 441;
        if (!flag[a][p]) selT[s++] = t;
      }
    }
  }
  __syncthreads();
  if (tid < 20) {
    int t = selT[tid];
    int ch = t / 441, p = t % 441, i = p / 21, j = p % 21;
    int a = ch >> 2, c = ch & 3;
    float v = bbb[ch];
    #pragma unroll
    for (int c2 = 0; c2 < 2; c2++)
      #pragma unroll
      for (int dy = 0; dy < 3; dy++)
        #pragma unroll
        for (int dx = 0; dx < 3; dx++)
          v += ys[c2][i + dy][j + dx] * bbw[ch * 18 + c2 * 9 + dy * 3 + dx];
    offv[tid] = v;
    float sz = (a < 3) ? 1.f : 2.f;
    int am = a % 3;
    float ar = (am == 0) ? 0.5f : (am == 1 ? 1.f : 2.f);
    float base;
    if (c == 0) base = 0.f;
    else if (c == 1) base = sz * -(ar - 1.f) * 0.5f;
    else if (c == 2) base = sz;
    else base = sz * (1.f + (ar - 1.f) * 0.5f);
    anchv[tid] = base + ((c & 1) ? (float)j : (float)i);
  }
  __syncthreads();
  if (tid < 5) {
    int k = tid;
    float o0 = offv[4 * k], o1 = offv[4 * k + 1], o2 = offv[4 * k + 2], o3 = offv[4 * k + 3];
    float a0 = anchv[4 * k], a2 = anchv[4 * k + 2], a3 = anchv[4 * k + 3];
    float p0 = fminf(fmaxf(o0 + a0 - a2 * 0.5f, 0.f), 21.f) * 50.f;
    float p1 = fminf(fmaxf(o1 - a3 * 0.5f, 0.f), 21.f) * 50.f;
    float p2 = fminf(fmaxf(o2 + a0 + a2 * 0.5f, 0.f), 21.f) * 50.f;
    float p3 = fminf(fmaxf(o3 + a3 * 0.5f, 0.f), 21.f) * 50.f;
    props_out[k * 4 + 0] = p0;
    props_out[k * 4 + 1] = p1;
    props_out[k * 4 + 2] = p2;
    props_out[k * 4 + 3] = p3;
    float x1 = rintf(p0), y1 = rintf(p1), x2 = rintf(p2), y2 = rintf(p3);
    float bwf = fmaxf(x2 - x1 + 1.f, 1.f) * 0.5f;
    float bhf = fmaxf(y2 - y1 + 1.f, 1.f) * 0.5f;
    for (int ph = 0; ph < 2; ph++)
      for (int pw = 0; pw < 2; pw++) {
        int hsv = (int)fminf(fmaxf(floorf((float)ph * bhf) + y1, 0.f), 1080.f);
        int hev = (int)fminf(fmaxf(ceilf((float)(ph + 1) * bhf) + y1, 0.f), 1080.f);
        int wsv = (int)fminf(fmaxf(floorf((float)pw * bwf) + x1, 0.f), 1080.f);
        int wev = (int)fminf(fmaxf(ceilf((float)(pw + 1) * bwf) + x1, 0.f), 1080.f);
        int idx = k * 4 + ph * 2 + pw;
        rects[idx * 4 + 0] = hsv;
        rects[idx * 4 + 1] = hev;
        rects[idx * 4 + 2] = wsv;
        rects[idx * 4 + 3] = wev;
      }
  }
  if (tid >= 32 && tid < 52) pooled_m[tid - 32] = 0x007FFFFFu;  // mapped(-inf)
}

// ============ K5: RoI max pool (atomicMax on order-preserving uint map) ============
__global__ __launch_bounds__(256) void k5_roipool(
    const float* __restrict__ red, const int* __restrict__ rects,
    unsigned* __restrict__ pooled_m) {
  const int cell = blockIdx.x;
  const int hs = rects[cell * 4 + 0], he = rects[cell * 4 + 1];
  const int wss = rects[cell * 4 + 2], wee = rects[cell * 4 + 3];
  const int nr = he - hs;
  if (nr <= 0 || wee <= wss) return;
  const int slice = blockIdx.y, nslice = gridDim.y;
  const int r0 = hs + (int)((long)nr * slice / nslice);
  const int r1 = hs + (int)((long)nr * (slice + 1) / nslice);
  float m = -INFINITY;
  for (int r = r0; r < r1; r++)
    for (int c = wss + (int)threadIdx.x; c < wee; c += 256)
      m = fmaxf(m, red[(size_t)r * FMD + c]);
  __shared__ float part[256];
  part[threadIdx.x] = m;
  __syncthreads();
  for (int s = 128; s > 0; s >>= 1) {
    if ((int)threadIdx.x < s) part[threadIdx.x] = fmaxf(part[threadIdx.x], part[threadIdx.x + s]);
    __syncthreads();
  }
  if (threadIdx.x == 0 && part[0] > -INFINITY) {
    unsigned u = __float_as_uint(part[0]);
    u = (u & 0x80000000u) ? ~u : (u | 0x80000000u);
    atomicMax(&pooled_m[cell], u);
  }
}

// ============ K6: fc / box / cls heads -> d_out (30 floats) ============
__global__ void k6_heads(
    const unsigned* __restrict__ pooled_m, const float* __restrict__ props,
    const float* __restrict__ fcw, const float* __restrict__ fcb,
    const float* __restrict__ bxw, const float* __restrict__ bxb,
    const float* __restrict__ clw, const float* __restrict__ clb,
    float* __restrict__ out) {
  if (threadIdx.x != 0 || blockIdx.x != 0) return;
  float pooled[5][4];
  for (int i = 0; i < 20; i++) {
    unsigned u = pooled_m[i];
    float f = (u & 0x80000000u) ? __uint_as_float(u ^ 0x80000000u) : __uint_as_float(~u);
    if (!isfinite(f)) f = 0.f;
    pooled[i / 4][i % 4] = f;
  }
  for (int k = 0; k < 5; k++) {
    float fc[12];
    for (int m = 0; m < 12; m++) {
      float v = fcb[m];
      for (int n = 0; n < 4; n++) v += pooled[k][n] * fcw[m * 4 + n];
      fc[m] = v;
    }
    float bo[4];
    for (int c = 0; c < 4; c++) {
      float v = bxb[c];
      for (int m = 0; m < 12; m++) v += fc[m] * bxw[c * 12 + m];
      bo[c] = v;
    }
    float p0 = props[k * 4], p1 = props[k * 4 + 1], p2 = props[k * 4 + 2], p3 = props[k * 4 + 3];
    out[k * 4 + 0] = fminf(fmaxf(p0 + bo[0] - bo[2] * 0.5f, 0.f), 3.f);
    out[k * 4 + 1] = fminf(fmaxf(p1 - bo[3] * 0.5f, 0.f), 1.f);
    out[k * 4 + 2] = fminf(fmaxf(p2 + bo[0] + bo[2] * 0.5f, 0.f), 3.f);
    out[k * 4 + 3] = fminf(fmaxf(p3 + bo[3] * 0.5f, 0.f), 1.f);
    float l0 = clb[0], l1 = clb[1];
    for (int m = 0; m < 12; m++) {
      l0 += fc[m] * clw[m];
      l1 += fc[m] * clw[12 + m];
    }
    float mx = fmaxf(l0, l1);
    float e0 = expf(l0 - mx), e1 = expf(l1 - mx);
    out[20 + k * 2 + 0] = e0 / (e0 + e1);
    out[20 + k * 2 + 1] = e1 / (e0 + e1);
  }
}

extern "C" void kernel_launch(void* const* d_in, const int* in_sizes, int n_in,
                              void* d_out, int out_size, void* d_ws, size_t ws_size,
                              hipStream_t stream) {
  const float* x   = (const float*)d_in[0];
  const float* w1  = (const float*)d_in[1];
  const float* b1  = (const float*)d_in[2];
  const float* w2  = (const float*)d_in[3];
  const float* b2  = (const float*)d_in[4];
  const float* w3  = (const float*)d_in[5];
  const float* b3  = (const float*)d_in[6];
  const float* w4  = (const float*)d_in[7];
  const float* b4  = (const float*)d_in[8];
  const float* rw  = (const float*)d_in[9];
  const float* rb  = (const float*)d_in[10];
  const float* bbw = (const float*)d_in[11];
  const float* bbb = (const float*)d_in[12];
  const float* clw = (const float*)d_in[13];
  const float* clb = (const float*)d_in[14];
  const float* fcw = (const float*)d_in[15];
  const float* fcb = (const float*)d_in[16];
  const float* bxw = (const float*)d_in[17];
  const float* bxb = (const float*)d_in[18];
  const float* c2w = (const float*)d_in[19];
  const float* c2b = (const float*)d_in[20];

  float* ws = (float*)d_ws;
  float* h2 = ws + H2_OFF;
  float* red = ws + RED_OFF;
  float* y = ws + Y_OFF;
  float* props = ws + PROPS_OFF;
  int* rects = (int*)(ws + RECTS_OFF);
  unsigned* pooled_m = (unsigned*)(ws + POOL_OFF);

  k1_stream<<<1296, 256, 0, stream>>>(x, w1, b1, w2, b2, h2);
  k2_backbone2<<<dim3(72, 72), 256, 0, stream>>>(h2, w3, b3, w4, b4, red);
  k3_rpnconv<<<441, 256, 0, stream>>>(red, rw, rb, y);
  k4_select<<<1, 512, 0, stream>>>(y, bbw, bbb, clw, clb, props, rects, pooled_m);
  k5_roipool<<<dim3(20, 16), 256, 0, stream>>>(red, rects, pooled_m);
  k6_heads<<<1, 64, 0, stream>>>(pooled_m, props, fcw, fcb, bxw, bxb, c2w, c2b,
                                 (float*)d_out);
}